// Round 9
// baseline (89.363 us; speedup 1.0000x reference)
//
#include <hip/hip_runtime.h>
#include <stdint.h>

// YOLO v1 loss: BATCH=16384, S=7, B=2, C=20, D=30 floats per cell.
// NCELLS = 802816 = 12544 tiles * 64 cells.
// Single fused kernel: 1280 persistent 1-wave blocks (5/CU exactly resident),
// double-buffered LDS pipeline with counted vmcnt; last-finished block does
// the final reduction (deterministic: reduce order is fixed lane-strided).
#define NTILES 12544
#define GBLK 1280            // main blocks; also the partial count (= 5 * 256 CUs)
#define F4_PER_TILE 480      // 64 cells * 30 floats / 4 floats-per-float4

// async global->LDS, 16B per lane. LDS dest = wave-uniform base + lane*16.
#define ASYNC_CP16(gsrc, ldst)                                                     \
    __builtin_amdgcn_global_load_lds(                                              \
        (const __attribute__((address_space(1))) unsigned int*)(gsrc),             \
        (__attribute__((address_space(3))) unsigned int*)(ldst), 16, 0, 0)

__device__ __forceinline__ void merge2(unsigned& a1, unsigned& a2,
                                       unsigned b1, unsigned b2) {
    // (a1<=a2), (b1<=b2) -> two smallest of the union
    const unsigned n1 = min(a1, b1);
    const unsigned n2 = min(max(a1, b1), min(a2, b2));
    a1 = n1; a2 = n2;
}

// 16 fill instructions per tile (7 full-wave + 1 half-wave, x2 tensors)
__device__ __forceinline__ void issue_tile_fills(
    const float* __restrict__ pred, const float* __restrict__ targ,
    int tile, float* sp, float* st, int lane)
{
    const float4* p4 = reinterpret_cast<const float4*>(pred) + (size_t)tile * F4_PER_TILE;
    const float4* t4 = reinterpret_cast<const float4*>(targ) + (size_t)tile * F4_PER_TILE;
#pragma unroll
    for (int q = 0; q < 7; ++q) {
        ASYNC_CP16(p4 + lane + 64 * q, sp + 256 * q);
        ASYNC_CP16(t4 + lane + 64 * q, st + 256 * q);
    }
    if (lane < 32) {
        ASYNC_CP16(p4 + lane + 448, sp + 1792);
        ASYNC_CP16(t4 + lane + 448, st + 1792);
    }
}

// ws layout:
//   float sums[4][GBLK]   at float offset 0       (loc_sq, hit, noobj, cls)
//   uint  mins[2][GBLK]   at float offset 4*GBLK  (min, second-min contained idx)
//   uint  counter         at float offset 6*GBLK  (memset to 0 every call)

__global__ __launch_bounds__(64) void yolo_fused_kernel(
    const float* __restrict__ pred, const float* __restrict__ targ,
    float* __restrict__ ws_sums, unsigned* __restrict__ ws_mins,
    unsigned* __restrict__ counter, float* __restrict__ out)
{
    // two buffers of (1920 pred + 1920 targ) floats = 30720 B total
    __shared__ __align__(16) float smem[7680];

    const int lane = threadIdx.x;       // 0..63, single wave
    const int blk  = blockIdx.x;
    const int n    = (blk < (NTILES - 9 * GBLK)) ? 10 : 9;   // tiles for this block

    float acc_loc = 0.0f, acc_hit = 0.0f, acc_noobj = 0.0f, acc_cls = 0.0f;
    unsigned m1 = 0xFFFFFFFFu, m2 = 0xFFFFFFFFu;

    // ---- prologue: fill both buffers (tiles r=0,1) ----
    issue_tile_fills(pred, targ, blk,        smem,        smem + 1920, lane);
    issue_tile_fills(pred, targ, blk + GBLK, smem + 3840, smem + 5760, lane);

    for (int r = 0; r < n; ++r) {
        float* sp = smem + (r & 1) * 3840;
        float* st = sp + 1920;

        // current tile's 16 fills landed; next tile's 16 may stay in flight
        if (r < n - 1) asm volatile("s_waitcnt vmcnt(16)" ::: "memory");
        else           asm volatile("s_waitcnt vmcnt(0)"  ::: "memory");
        __builtin_amdgcn_sched_barrier(0);

        // ---- read this thread's 30+30 floats from LDS ----
        float pv[30], tv[30];
        const float2* spp = reinterpret_cast<const float2*>(sp) + lane * 15;
        const float2* stp = reinterpret_cast<const float2*>(st) + lane * 15;
#pragma unroll
        for (int i = 0; i < 15; ++i) { float2 v = spp[i]; pv[2*i] = v.x; pv[2*i+1] = v.y; }
#pragma unroll
        for (int i = 0; i < 15; ++i) { float2 v = stp[i]; tv[2*i] = v.x; tv[2*i+1] = v.y; }

        // ds_reads retired -> safe to overwrite this buffer with tile r+2 fills
        asm volatile("s_waitcnt lgkmcnt(0)" ::: "memory");
        __builtin_amdgcn_sched_barrier(0);
        if (r < n - 2)
            issue_tile_fills(pred, targ, blk + (r + 2) * GBLK, sp, st, lane);

        const int cell = (blk + r * GBLK) * 64 + lane;
        const float obj = (tv[0] == 1.0f) ? 1.0f : 0.0f;

        // ---- class loss ----
        float cls = 0.0f;
#pragma unroll
        for (int i = 10; i < 30; ++i) { float d = pv[i] - tv[i]; cls = fmaf(d, d, cls); }
        acc_cls = fmaf(cls, obj, acc_cls);

        // ---- gt box 0 corners (mirrors reference arithmetic) ----
        const float g0x = tv[2] / 7.0f - 0.5f * tv[4];
        const float g0y = tv[3] / 7.0f - 0.5f * tv[5];
        const float g1x = tv[2] / 7.0f + 0.5f * tv[4];
        const float g1y = tv[3] / 7.0f + 0.5f * tv[5];
        const float area_g = (g1x - g0x) * (g1y - g0y);

        // ---- IoUs for both pred boxes vs gt box 0 ----
        float iou[2];
#pragma unroll
        for (int b = 0; b < 2; ++b) {
            const float px = pv[2 + 4*b], py = pv[3 + 4*b];
            const float pw = pv[4 + 4*b], ph = pv[5 + 4*b];
            const float a0x = px / 7.0f - 0.5f * pw, a0y = py / 7.0f - 0.5f * ph;
            const float a1x = px / 7.0f + 0.5f * pw, a1y = py / 7.0f + 0.5f * ph;
            const float ltx = fmaxf(a0x, g0x), lty = fmaxf(a0y, g0y);
            const float rbx = fminf(a1x, g1x), rby = fminf(a1y, g1y);
            const float ww = fmaxf(rbx - ltx, 0.0f), hh = fmaxf(rby - lty, 0.0f);
            const float inter  = ww * hh;
            const float area_a = (a1x - a0x) * (a1y - a0y);
            iou[b] = inter / (area_a + area_g - inter);
        }
        // jnp.argmax tie-break: first index wins
        const int resp = (iou[1] > iou[0]) ? 1 : 0;

#pragma unroll
        for (int b = 0; b < 2; ++b) {
            const bool m = (obj != 0.0f) && (b == resp);
            const float pc = pv[b];
            if (m) {
                const float d = pc - iou[b];
                acc_hit = fmaf(d, d, acc_hit);
                float sq = 0.0f;
#pragma unroll
                for (int i = 0; i < 4; ++i) {
                    const float a = pv[2 + 4*b + i], g = tv[2 + 4*b + i];
                    const float ds = sqrtf(a) - sqrtf(g);
                    sq = fmaf(ds, ds, sq);
                }
                acc_loc += sq;
                merge2(m1, m2, (unsigned)(cell * 2 + b), 0xFFFFFFFFu);
            } else {
                acc_noobj = fmaf(pc, pc, acc_noobj);
            }
        }
    }

    // ---- in-wave butterfly reduction (no LDS, no barriers) ----
#pragma unroll
    for (int mask = 32; mask > 0; mask >>= 1) {
        acc_loc   += __shfl_xor(acc_loc,   mask);
        acc_hit   += __shfl_xor(acc_hit,   mask);
        acc_noobj += __shfl_xor(acc_noobj, mask);
        acc_cls   += __shfl_xor(acc_cls,   mask);
        const unsigned b1 = (unsigned)__shfl_xor((int)m1, mask);
        const unsigned b2 = (unsigned)__shfl_xor((int)m2, mask);
        merge2(m1, m2, b1, b2);
    }
    if (lane == 0) {
        ws_sums[0 * GBLK + blk] = acc_loc;
        ws_sums[1 * GBLK + blk] = acc_hit;
        ws_sums[2 * GBLK + blk] = acc_noobj;
        ws_sums[3 * GBLK + blk] = acc_cls;
        ws_mins[0 * GBLK + blk] = m1;
        ws_mins[1 * GBLK + blk] = m2;
    }

    // ---- last-block-done: publish partials, count up, last block finalizes ----
    __threadfence();                         // release: partials visible device-wide
    int old = 0;
    if (lane == 0) old = (int)atomicAdd(counter, 1u);
    old = __shfl(old, 0);
    if (old != GBLK - 1) return;

    __threadfence();                         // acquire: see all blocks' partials

    // wave-wide final reduce over GBLK partials (fixed order -> deterministic)
    double s0 = 0.0, s1 = 0.0, s2 = 0.0, s3 = 0.0;
    unsigned M1 = 0xFFFFFFFFu, M2 = 0xFFFFFFFFu;
    for (int i = lane; i < GBLK; i += 64) {
        s0 += (double)ws_sums[0 * GBLK + i];
        s1 += (double)ws_sums[1 * GBLK + i];
        s2 += (double)ws_sums[2 * GBLK + i];
        s3 += (double)ws_sums[3 * GBLK + i];
        merge2(M1, M2, ws_mins[0 * GBLK + i], ws_mins[1 * GBLK + i]);
    }
#pragma unroll
    for (int mask = 32; mask > 0; mask >>= 1) {
        s0 += __shfl_xor(s0, mask);
        s1 += __shfl_xor(s1, mask);
        s2 += __shfl_xor(s2, mask);
        s3 += __shfl_xor(s3, mask);
        const unsigned b1 = (unsigned)__shfl_xor((int)M1, mask);
        const unsigned b2 = (unsigned)__shfl_xor((int)M2, mask);
        merge2(M1, M2, b1, b2);
    }

    if (lane == 0) {
        double loc = s0;
        // first two responsible boxes (global flat order) use plain instead of sq
        const unsigned mm[2] = { M1, M2 };
#pragma unroll
        for (int s = 0; s < 2; ++s) {
            const unsigned idx = mm[s];
            if (idx != 0xFFFFFFFFu) {
                const int cell = (int)(idx >> 1);
                const int b    = (int)(idx & 1u);
                const float* p = pred + (size_t)cell * 30 + 2 + 4*b;
                const float* t = targ + (size_t)cell * 30 + 2 + 4*b;
                float plain = 0.0f, sq = 0.0f;
#pragma unroll
                for (int i = 0; i < 4; ++i) {
                    const float a = p[i], g = t[i];
                    const float dd = a - g;  plain = fmaf(dd, dd, plain);
                    const float ds = sqrtf(a) - sqrtf(g); sq = fmaf(ds, ds, sq);
                }
                loc += (double)plain - (double)sq;
            }
        }
        const double total = (5.0 * loc + s1 + 0.5 * s2 + s3) / 16384.0;
        out[0] = (float)total;
    }
}

extern "C" void kernel_launch(void* const* d_in, const int* in_sizes, int n_in,
                              void* d_out, int out_size, void* d_ws, size_t ws_size,
                              hipStream_t stream) {
    const float* pred = (const float*)d_in[0];
    const float* targ = (const float*)d_in[1];
    float* out = (float*)d_out;

    float* ws_sums = (float*)d_ws;                                            // 4*GBLK floats
    unsigned* ws_mins = (unsigned*)((char*)d_ws + sizeof(float) * 4 * GBLK);  // 2*GBLK uints
    unsigned* counter = (unsigned*)((char*)d_ws + sizeof(float) * 6 * GBLK);  // 1 uint

    hipMemsetAsync(counter, 0, sizeof(unsigned), stream);
    yolo_fused_kernel<<<GBLK, 64, 0, stream>>>(pred, targ, ws_sums, ws_mins, counter, out);
}

// Round 10
// 41.062 us; speedup vs baseline: 2.1763x; 2.1763x over previous
//
#include <hip/hip_runtime.h>
#include <stdint.h>

// YOLO v1 loss: BATCH=16384, S=7, B=2, C=20, D=30 floats per cell.
// NCELLS = 802816 = 12544 tiles * 64 cells.
// Main: 1280 persistent 1-wave blocks (5/CU exactly resident), double-buffered
// LDS pipeline with counted vmcnt (no barriers, no full drains in steady state).
// [Round 9 post-mortem: last-block-done fusion with per-block __threadfence()
//  regressed 2x — device-scope fence = L2 writeback on multi-XCD. Reverted.]
#define NTILES 12544
#define GBLK 1280            // main blocks; also the partial count (= 5 * 256 CUs)
#define F4_PER_TILE 480      // 64 cells * 30 floats / 4 floats-per-float4

// async global->LDS, 16B per lane. LDS dest = wave-uniform base + lane*16.
#define ASYNC_CP16(gsrc, ldst)                                                     \
    __builtin_amdgcn_global_load_lds(                                              \
        (const __attribute__((address_space(1))) unsigned int*)(gsrc),             \
        (__attribute__((address_space(3))) unsigned int*)(ldst), 16, 0, 0)

__device__ __forceinline__ void merge2(unsigned& a1, unsigned& a2,
                                       unsigned b1, unsigned b2) {
    // (a1<=a2), (b1<=b2) -> two smallest of the union
    const unsigned n1 = min(a1, b1);
    const unsigned n2 = min(max(a1, b1), min(a2, b2));
    a1 = n1; a2 = n2;
}

// 16 fill instructions per tile (7 full-wave + 1 half-wave, x2 tensors)
__device__ __forceinline__ void issue_tile_fills(
    const float* __restrict__ pred, const float* __restrict__ targ,
    int tile, float* sp, float* st, int lane)
{
    const float4* p4 = reinterpret_cast<const float4*>(pred) + (size_t)tile * F4_PER_TILE;
    const float4* t4 = reinterpret_cast<const float4*>(targ) + (size_t)tile * F4_PER_TILE;
#pragma unroll
    for (int q = 0; q < 7; ++q) {
        ASYNC_CP16(p4 + lane + 64 * q, sp + 256 * q);
        ASYNC_CP16(t4 + lane + 64 * q, st + 256 * q);
    }
    if (lane < 32) {
        ASYNC_CP16(p4 + lane + 448, sp + 1792);
        ASYNC_CP16(t4 + lane + 448, st + 1792);
    }
}

// ws layout (SoA, every slot written every call):
//   float sums[4][GBLK]  at float offset 0       (loc_sq, hit, noobj, cls)
//   uint  mins[2][GBLK]  at float offset 4*GBLK  (min, second-min contained idx)

__global__ __launch_bounds__(64) void yolo_main_kernel(
    const float* __restrict__ pred, const float* __restrict__ targ,
    float* __restrict__ ws_sums, unsigned* __restrict__ ws_mins)
{
    // two buffers of (1920 pred + 1920 targ) floats = 30720 B total
    __shared__ __align__(16) float smem[7680];

    const int lane = threadIdx.x;       // 0..63, single wave
    const int blk  = blockIdx.x;
    const int n    = (blk < (NTILES - 9 * GBLK)) ? 10 : 9;   // tiles for this block

    float acc_loc = 0.0f, acc_hit = 0.0f, acc_noobj = 0.0f, acc_cls = 0.0f;
    unsigned m1 = 0xFFFFFFFFu, m2 = 0xFFFFFFFFu;

    // ---- prologue: fill both buffers (tiles r=0,1) ----
    issue_tile_fills(pred, targ, blk,        smem,        smem + 1920, lane);
    issue_tile_fills(pred, targ, blk + GBLK, smem + 3840, smem + 5760, lane);

    for (int r = 0; r < n; ++r) {
        float* sp = smem + (r & 1) * 3840;
        float* st = sp + 1920;

        // current tile's 16 fills landed; next tile's 16 may stay in flight
        if (r < n - 1) asm volatile("s_waitcnt vmcnt(16)" ::: "memory");
        else           asm volatile("s_waitcnt vmcnt(0)"  ::: "memory");
        __builtin_amdgcn_sched_barrier(0);

        // ---- read this thread's 30+30 floats from LDS ----
        float pv[30], tv[30];
        const float2* spp = reinterpret_cast<const float2*>(sp) + lane * 15;
        const float2* stp = reinterpret_cast<const float2*>(st) + lane * 15;
#pragma unroll
        for (int i = 0; i < 15; ++i) { float2 v = spp[i]; pv[2*i] = v.x; pv[2*i+1] = v.y; }
#pragma unroll
        for (int i = 0; i < 15; ++i) { float2 v = stp[i]; tv[2*i] = v.x; tv[2*i+1] = v.y; }

        // ds_reads retired -> safe to overwrite this buffer with tile r+2 fills
        asm volatile("s_waitcnt lgkmcnt(0)" ::: "memory");
        __builtin_amdgcn_sched_barrier(0);
        if (r < n - 2)
            issue_tile_fills(pred, targ, blk + (r + 2) * GBLK, sp, st, lane);

        const int cell = (blk + r * GBLK) * 64 + lane;
        const float obj = (tv[0] == 1.0f) ? 1.0f : 0.0f;

        // ---- class loss ----
        float cls = 0.0f;
#pragma unroll
        for (int i = 10; i < 30; ++i) { float d = pv[i] - tv[i]; cls = fmaf(d, d, cls); }
        acc_cls = fmaf(cls, obj, acc_cls);

        // ---- gt box 0 corners (mirrors reference arithmetic) ----
        const float g0x = tv[2] / 7.0f - 0.5f * tv[4];
        const float g0y = tv[3] / 7.0f - 0.5f * tv[5];
        const float g1x = tv[2] / 7.0f + 0.5f * tv[4];
        const float g1y = tv[3] / 7.0f + 0.5f * tv[5];
        const float area_g = (g1x - g0x) * (g1y - g0y);

        // ---- IoUs for both pred boxes vs gt box 0 ----
        float iou[2];
#pragma unroll
        for (int b = 0; b < 2; ++b) {
            const float px = pv[2 + 4*b], py = pv[3 + 4*b];
            const float pw = pv[4 + 4*b], ph = pv[5 + 4*b];
            const float a0x = px / 7.0f - 0.5f * pw, a0y = py / 7.0f - 0.5f * ph;
            const float a1x = px / 7.0f + 0.5f * pw, a1y = py / 7.0f + 0.5f * ph;
            const float ltx = fmaxf(a0x, g0x), lty = fmaxf(a0y, g0y);
            const float rbx = fminf(a1x, g1x), rby = fminf(a1y, g1y);
            const float ww = fmaxf(rbx - ltx, 0.0f), hh = fmaxf(rby - lty, 0.0f);
            const float inter  = ww * hh;
            const float area_a = (a1x - a0x) * (a1y - a0y);
            iou[b] = inter / (area_a + area_g - inter);
        }
        // jnp.argmax tie-break: first index wins
        const int resp = (iou[1] > iou[0]) ? 1 : 0;

#pragma unroll
        for (int b = 0; b < 2; ++b) {
            const bool m = (obj != 0.0f) && (b == resp);
            const float pc = pv[b];
            if (m) {
                const float d = pc - iou[b];
                acc_hit = fmaf(d, d, acc_hit);
                float sq = 0.0f;
#pragma unroll
                for (int i = 0; i < 4; ++i) {
                    const float a = pv[2 + 4*b + i], g = tv[2 + 4*b + i];
                    const float ds = sqrtf(a) - sqrtf(g);
                    sq = fmaf(ds, ds, sq);
                }
                acc_loc += sq;
                merge2(m1, m2, (unsigned)(cell * 2 + b), 0xFFFFFFFFu);
            } else {
                acc_noobj = fmaf(pc, pc, acc_noobj);
            }
        }
    }

    // ---- in-wave butterfly reduction (no LDS, no barriers) ----
#pragma unroll
    for (int mask = 32; mask > 0; mask >>= 1) {
        acc_loc   += __shfl_xor(acc_loc,   mask);
        acc_hit   += __shfl_xor(acc_hit,   mask);
        acc_noobj += __shfl_xor(acc_noobj, mask);
        acc_cls   += __shfl_xor(acc_cls,   mask);
        const unsigned b1 = (unsigned)__shfl_xor((int)m1, mask);
        const unsigned b2 = (unsigned)__shfl_xor((int)m2, mask);
        merge2(m1, m2, b1, b2);
    }
    if (lane == 0) {
        ws_sums[0 * GBLK + blk] = acc_loc;
        ws_sums[1 * GBLK + blk] = acc_hit;
        ws_sums[2 * GBLK + blk] = acc_noobj;
        ws_sums[3 * GBLK + blk] = acc_cls;
        ws_mins[0 * GBLK + blk] = m1;
        ws_mins[1 * GBLK + blk] = m2;
    }
}

__global__ __launch_bounds__(1024) void yolo_finalize_kernel(
    const float* __restrict__ pred, const float* __restrict__ targ,
    const float* __restrict__ ws_sums, const unsigned* __restrict__ ws_mins,
    float* __restrict__ out)
{
    const int tid = threadIdx.x;
    double s0 = 0.0, s1 = 0.0, s2 = 0.0, s3 = 0.0;
    unsigned m1 = 0xFFFFFFFFu, m2 = 0xFFFFFFFFu;
    for (int i = tid; i < GBLK; i += 1024) {
        s0 += (double)ws_sums[0 * GBLK + i];
        s1 += (double)ws_sums[1 * GBLK + i];
        s2 += (double)ws_sums[2 * GBLK + i];
        s3 += (double)ws_sums[3 * GBLK + i];
        merge2(m1, m2, ws_mins[0 * GBLK + i], ws_mins[1 * GBLK + i]);
    }
    __shared__ double dred[4][1024];
    __shared__ unsigned fm1[1024], fm2[1024];
    dred[0][tid] = s0; dred[1][tid] = s1; dred[2][tid] = s2; dred[3][tid] = s3;
    fm1[tid] = m1; fm2[tid] = m2;
    __syncthreads();
#pragma unroll
    for (int s = 512; s > 0; s >>= 1) {
        if (tid < s) {
            dred[0][tid] += dred[0][tid + s];
            dred[1][tid] += dred[1][tid + s];
            dred[2][tid] += dred[2][tid + s];
            dred[3][tid] += dred[3][tid + s];
            unsigned a1 = fm1[tid], a2 = fm2[tid];
            merge2(a1, a2, fm1[tid + s], fm2[tid + s]);
            fm1[tid] = a1; fm2[tid] = a2;
        }
        __syncthreads();
    }
    if (tid == 0) {
        double loc = dred[0][0];
        const double hit = dred[1][0], noobj = dred[2][0], cls = dred[3][0];
        const unsigned mm[2] = { fm1[0], fm2[0] };
        // first two responsible boxes (global flat order) use plain instead of sq
#pragma unroll
        for (int s = 0; s < 2; ++s) {
            const unsigned idx = mm[s];
            if (idx != 0xFFFFFFFFu) {
                const int cell = (int)(idx >> 1);
                const int b    = (int)(idx & 1u);
                const float* p = pred + (size_t)cell * 30 + 2 + 4*b;
                const float* t = targ + (size_t)cell * 30 + 2 + 4*b;
                float plain = 0.0f, sq = 0.0f;
#pragma unroll
                for (int i = 0; i < 4; ++i) {
                    const float a = p[i], g = t[i];
                    const float dd = a - g;  plain = fmaf(dd, dd, plain);
                    const float ds = sqrtf(a) - sqrtf(g); sq = fmaf(ds, ds, sq);
                }
                loc += (double)plain - (double)sq;
            }
        }
        const double total = (5.0 * loc + hit + 0.5 * noobj + cls) / 16384.0;
        out[0] = (float)total;
    }
}

extern "C" void kernel_launch(void* const* d_in, const int* in_sizes, int n_in,
                              void* d_out, int out_size, void* d_ws, size_t ws_size,
                              hipStream_t stream) {
    const float* pred = (const float*)d_in[0];
    const float* targ = (const float*)d_in[1];
    float* out = (float*)d_out;

    float* ws_sums = (float*)d_ws;                                        // 4*GBLK floats
    unsigned* ws_mins = (unsigned*)((char*)d_ws + sizeof(float) * 4 * GBLK);  // 2*GBLK uints

    yolo_main_kernel<<<GBLK, 64, 0, stream>>>(pred, targ, ws_sums, ws_mins);
    yolo_finalize_kernel<<<1, 1024, 0, stream>>>(pred, targ, ws_sums, ws_mins, out);
}